// Round 1
// baseline (855.130 us; speedup 1.0000x reference)
//
#include <hip/hip_runtime.h>

typedef short short8 __attribute__((ext_vector_type(8)));
typedef float floatx4 __attribute__((ext_vector_type(4)));

#define LDSS 264  // LDS row stride in bf16 elems (256 + 8) -> conflict-free b128 frag reads

__device__ __forceinline__ unsigned short f2bf(float x) {
  union { float f; unsigned int u; } c; c.f = x;
  return (unsigned short)((c.u + 0x7FFFu + ((c.u >> 16) & 1u)) >> 16);
}

__global__ void k_zero(int* p, int n) {
  int i = blockIdx.x * blockDim.x + threadIdx.x;
  if (i < n) p[i] = 0;
}

__global__ void k_hist(const int* __restrict__ gid, int L, int* __restrict__ counts) {
  int i = blockIdx.x * blockDim.x + threadIdx.x;
  if (i < L) atomicAdd(&counts[gid[i]], 1);
}

// single-block scan of G counts -> exclusive offsets[G+1], cursor = copy of offsets
__global__ void k_scan(const int* __restrict__ counts, int* __restrict__ offsets,
                       int* __restrict__ cursor, int G) {
  __shared__ int sc[1024];
  int t = threadIdx.x;
  int items = (G + 1023) >> 10;
  int base = t * items;
  int s = 0;
  for (int i = 0; i < items; ++i) { int idx = base + i; if (idx < G) s += counts[idx]; }
  sc[t] = s;
  __syncthreads();
  for (int off = 1; off < 1024; off <<= 1) {
    int v = (t >= off) ? sc[t - off] : 0;
    __syncthreads();
    if (t >= off) sc[t] += v;
    __syncthreads();
  }
  int run = (t == 0) ? 0 : sc[t - 1];
  for (int i = 0; i < items; ++i) {
    int idx = base + i;
    if (idx < G) { offsets[idx] = run; cursor[idx] = run; run += counts[idx]; }
  }
  if (t == 1023) offsets[G] = sc[1023];
}

__global__ void k_scatter(const int* __restrict__ gid, int L, int* __restrict__ cursor,
                          int* __restrict__ order) {
  int i = blockIdx.x * blockDim.x + threadIdx.x;
  if (i < L) {
    int g = gid[i];
    int pos = atomicAdd(&cursor[g], 1);
    order[pos] = i;
  }
}

// Combined weight matrix W2 [512][256] bf16, rows interleaved so that
// j2 = 128*w + 64*half + c  maps to  d = 64*w + c   (half 0 = key, 1 = value).
// => wave w's 128 rows cover d in [64w, 64w+64) for BOTH projections.
__global__ void k_prepw(const float* __restrict__ keyW, const float* __restrict__ valW,
                        unsigned short* __restrict__ W2) {
  int j2 = blockIdx.x;
  int k = threadIdx.x;
  int wv = j2 >> 7, half = (j2 >> 6) & 1, c = j2 & 63;
  int d = (wv << 6) + c;
  const float* src = half ? valW : keyW;
  W2[j2 * 256 + k] = f2bf(src[d * 256 + k]);
}

__launch_bounds__(256)
__global__ void k_fused(const float* __restrict__ fnode,
                        const unsigned short* __restrict__ W2,
                        const float* __restrict__ key_b, const float* __restrict__ value_b,
                        const float* __restrict__ gamma, const float* __restrict__ beta,
                        const int* __restrict__ order, const int* __restrict__ offsets,
                        float* __restrict__ out) {
  __shared__ __align__(16) unsigned short As[64 * LDSS];
  __shared__ float fg[256];
  __shared__ float red[8];

  const int g = blockIdx.x;
  const int t = threadIdx.x;
  const int lane = t & 63;
  const int w = t >> 6;        // wave 0..3 -> d range [64w, 64w+64)
  const int lcol = lane & 15;
  const int lrow = lane >> 4;

  const int s0 = offsets[g];
  const int n_g = offsets[g + 1] - s0;

  // per-lane biases for the 4 n-frags this lane touches (d fixed per lane)
  float kb[4], vb[4];
#pragma unroll
  for (int nj = 0; nj < 4; ++nj) {
    int d = (w << 6) + (nj << 4) + lcol;
    kb[nj] = key_b[d];
    vb[nj] = value_b[d];
  }

  float den[4] = {0.f, 0.f, 0.f, 0.f};
  float num[4] = {0.f, 0.f, 0.f, 0.f};

  const unsigned short* W2w = W2 + ((size_t)(w << 7)) * 256;

  const int sr = t >> 2;  // staging row 0..63
  const int sq = t & 3;   // staging quarter (64 floats)

  for (int m0 = 0; m0 < n_g; m0 += 64) {
    const int valid = min(64, n_g - m0);

    // ---- stage A chunk (gathered rows, fp32 -> bf16) into LDS ----
    {
      const bool vr = (sr < valid);
      const float* src = nullptr;
      if (vr) src = fnode + (size_t)order[s0 + m0 + sr] * 256 + sq * 64;
      unsigned short* dst = As + sr * LDSS + sq * 64;
#pragma unroll
      for (int it = 0; it < 16; ++it) {
        int i2 = (it + sq * 4) & 15;  // rotate per-quarter -> conflict-free ds_write
        ushort4 h;
        if (vr) {
          const float4 v = reinterpret_cast<const float4*>(src)[i2];
          h.x = f2bf(v.x); h.y = f2bf(v.y); h.z = f2bf(v.z); h.w = f2bf(v.w);
        } else {
          h.x = 0; h.y = 0; h.z = 0; h.w = 0;
        }
        *reinterpret_cast<ushort4*>(dst + i2 * 4) = h;
      }
    }
    __syncthreads();

    // ---- MFMA: A[64x256] x W2w[128x256]^T -> acc[4 m][8 n] ----
    floatx4 acc[4][8];
#pragma unroll
    for (int mi = 0; mi < 4; ++mi)
#pragma unroll
      for (int nj = 0; nj < 8; ++nj)
        acc[mi][nj] = (floatx4){0.f, 0.f, 0.f, 0.f};

#pragma unroll
    for (int kk = 0; kk < 8; ++kk) {
      const int kof = kk * 32 + lrow * 8;
      short8 afr[4];
#pragma unroll
      for (int mi = 0; mi < 4; ++mi)
        afr[mi] = *reinterpret_cast<const short8*>(&As[(mi * 16 + lcol) * LDSS + kof]);
#pragma unroll
      for (int nj = 0; nj < 8; ++nj) {
        const short8 bfr =
            *reinterpret_cast<const short8*>(&W2w[(size_t)(nj * 16 + lcol) * 256 + kof]);
#pragma unroll
        for (int mi = 0; mi < 4; ++mi)
          acc[mi][nj] = __builtin_amdgcn_mfma_f32_16x16x32_bf16(afr[mi], bfr, acc[mi][nj], 0, 0, 0);
      }
    }

    // ---- epilogue: ex = exp(attn + kb); den += ex; num += (val + vb) * ex ----
    // acc[mi][nj] (nj<4) is attn for d = 64w+16nj+lcol; acc[mi][nj+4] is val, SAME (r,d).
#pragma unroll
    for (int mi = 0; mi < 4; ++mi) {
#pragma unroll
      for (int qq = 0; qq < 4; ++qq) {
        const int r = mi * 16 + lrow * 4 + qq;
        const bool mvalid = (r < valid);
#pragma unroll
        for (int nj = 0; nj < 4; ++nj) {
          const float a = acc[mi][nj][qq] + kb[nj];
          const float v = acc[mi][nj + 4][qq] + vb[nj];
          const float e = mvalid ? __expf(a) : 0.f;
          den[nj] += e;
          num[nj] += v * e;
        }
      }
    }
    __syncthreads();  // As reads done; safe to restage next chunk
  }

  // ---- reduce the 4 row-groups (lanes l, l^16, l^32, l^48 share column d) ----
#pragma unroll
  for (int nj = 0; nj < 4; ++nj) {
    float ds = den[nj], ns = num[nj];
    ds += __shfl_xor(ds, 16, 64);
    ds += __shfl_xor(ds, 32, 64);
    ns += __shfl_xor(ns, 16, 64);
    ns += __shfl_xor(ns, 32, 64);
    if (lrow == 0) fg[(w << 6) + (nj << 4) + lcol] = ns / (ds + 1e-7f);
  }
  __syncthreads();

  // ---- LayerNorm over 256 features, write output row ----
  const float x = fg[t];
  float s = x, s2 = x * x;
#pragma unroll
  for (int o = 32; o > 0; o >>= 1) {
    s += __shfl_xor(s, o, 64);
    s2 += __shfl_xor(s2, o, 64);
  }
  if (lane == 0) { red[w] = s; red[4 + w] = s2; }
  __syncthreads();
  const float ts = red[0] + red[1] + red[2] + red[3];
  const float ts2 = red[4] + red[5] + red[6] + red[7];
  const float mu = ts * (1.f / 256.f);
  const float var = ts2 * (1.f / 256.f) - mu * mu;
  const float inv = rsqrtf(var + 1e-5f);
  out[(size_t)g * 256 + t] = (x - mu) * inv * gamma[t] + beta[t];
}

extern "C" void kernel_launch(void* const* d_in, const int* in_sizes, int n_in,
                              void* d_out, int out_size, void* d_ws, size_t ws_size,
                              hipStream_t stream) {
  const float* f_node   = (const float*)d_in[0];
  const float* key_W    = (const float*)d_in[1];
  const float* key_b    = (const float*)d_in[2];
  const float* value_W  = (const float*)d_in[3];
  const float* value_b  = (const float*)d_in[4];
  const float* gamma    = (const float*)d_in[5];
  const float* beta     = (const float*)d_in[6];
  const int*   graph_id = (const int*)d_in[7];
  const int L = in_sizes[0] / 256;
  const int G = out_size / 256;

  char* ws = (char*)d_ws;
  size_t off = 0;
  int* order = (int*)(ws + off); off += (size_t)L * 4;
  off = (off + 255) & ~(size_t)255;
  int* counts = (int*)(ws + off); off += (size_t)G * 4;
  int* offsets = (int*)(ws + off); off += (size_t)(G + 1) * 4;
  int* cursor = (int*)(ws + off); off += (size_t)G * 4;
  off = (off + 255) & ~(size_t)255;
  unsigned short* W2 = (unsigned short*)(ws + off); off += 512 * 256 * 2;

  k_zero<<<(G + 255) / 256, 256, 0, stream>>>(counts, G);
  k_hist<<<(L + 255) / 256, 256, 0, stream>>>(graph_id, L, counts);
  k_scan<<<1, 1024, 0, stream>>>(counts, offsets, cursor, G);
  k_scatter<<<(L + 255) / 256, 256, 0, stream>>>(graph_id, L, cursor, order);
  k_prepw<<<512, 256, 0, stream>>>(key_W, value_W, W2);
  k_fused<<<G, 256, 0, stream>>>(f_node, W2, key_b, value_b, gamma, beta, order, offsets,
                                 (float*)d_out);
}

// Round 2
// 656.066 us; speedup vs baseline: 1.3034x; 1.3034x over previous
//
#include <hip/hip_runtime.h>

typedef short short8 __attribute__((ext_vector_type(8)));
typedef unsigned short ushort8v __attribute__((ext_vector_type(8)));
typedef float floatx4 __attribute__((ext_vector_type(4)));

__device__ __forceinline__ unsigned short f2bf(float x) {
  union { float f; unsigned int u; } c; c.f = x;
  return (unsigned short)((c.u + 0x7FFFu + ((c.u >> 16) & 1u)) >> 16);
}

__global__ void k_zero(int* p, int n) {
  int i = blockIdx.x * blockDim.x + threadIdx.x;
  if (i < n) p[i] = 0;
}

__global__ void k_hist(const int* __restrict__ gid, int L, int* __restrict__ counts) {
  int i = blockIdx.x * blockDim.x + threadIdx.x;
  if (i < L) atomicAdd(&counts[gid[i]], 1);
}

// single-block scan of G counts -> exclusive offsets[G+1], cursor = copy of offsets
__global__ void k_scan(const int* __restrict__ counts, int* __restrict__ offsets,
                       int* __restrict__ cursor, int G) {
  __shared__ int sc[1024];
  int t = threadIdx.x;
  int items = (G + 1023) >> 10;
  int base = t * items;
  int s = 0;
  for (int i = 0; i < items; ++i) { int idx = base + i; if (idx < G) s += counts[idx]; }
  sc[t] = s;
  __syncthreads();
  for (int off = 1; off < 1024; off <<= 1) {
    int v = (t >= off) ? sc[t - off] : 0;
    __syncthreads();
    if (t >= off) sc[t] += v;
    __syncthreads();
  }
  int run = (t == 0) ? 0 : sc[t - 1];
  for (int i = 0; i < items; ++i) {
    int idx = base + i;
    if (idx < G) { offsets[idx] = run; cursor[idx] = run; run += counts[idx]; }
  }
  if (t == 1023) offsets[G] = sc[1023];
}

__global__ void k_scatter(const int* __restrict__ gid, int L, int* __restrict__ cursor,
                          int* __restrict__ order) {
  int i = blockIdx.x * blockDim.x + threadIdx.x;
  if (i < L) {
    int g = gid[i];
    int pos = atomicAdd(&cursor[g], 1);
    order[pos] = i;
  }
}

// Combined weight matrix W2 [512][256] bf16, rows interleaved so that
// j2 = 128*w + 64*half + c  maps to  d = 64*w + c   (half 0 = key, 1 = value).
__global__ void k_prepw(const float* __restrict__ keyW, const float* __restrict__ valW,
                        unsigned short* __restrict__ W2) {
  int j2 = blockIdx.x;
  int k = threadIdx.x;
  int wv = j2 >> 7, half = (j2 >> 6) & 1, c = j2 & 63;
  int d = (wv << 6) + c;
  const float* src = half ? valW : keyW;
  W2[j2 * 256 + k] = f2bf(src[d * 256 + k]);
}

__launch_bounds__(256)
__global__ void k_fused(const float* __restrict__ fnode,
                        const unsigned short* __restrict__ W2,
                        const float* __restrict__ key_b, const float* __restrict__ value_b,
                        const float* __restrict__ gamma, const float* __restrict__ beta,
                        const int* __restrict__ order, const int* __restrict__ offsets,
                        float* __restrict__ out) {
  // A tile: 64 rows x 256 bf16, linear 512B rows, XOR-swizzled (byte ^= (row&7)<<4)
  __shared__ __align__(16) unsigned short As[64 * 256];
  __shared__ int ord_s[64];
  __shared__ float fg[256];
  __shared__ float red[8];

  const int g = blockIdx.x;
  const int t = threadIdx.x;
  const int lane = t & 63;
  const int w = t >> 6;        // wave 0..3 -> d range [64w, 64w+64)
  const int lcol = lane & 15;
  const int lrow = lane >> 4;

  const int s0 = offsets[g];
  const int n_g = offsets[g + 1] - s0;

  // per-lane biases for the 4 n-frags this lane touches (d fixed per lane)
  float kb[4], vb[4];
#pragma unroll
  for (int nj = 0; nj < 4; ++nj) {
    int d = (w << 6) + (nj << 4) + lcol;
    kb[nj] = key_b[d];
    vb[nj] = value_b[d];
  }

  float den[4] = {0.f, 0.f, 0.f, 0.f};
  float num[4] = {0.f, 0.f, 0.f, 0.f};

  const unsigned short* W2l = W2 + ((size_t)(w << 7) + lcol) * 256;  // + nj*16*256 + kof
  char* AsB = (char*)As;

  const int shalf = lane >> 5;   // 0/1: which of the 2 rows this instr
  const int cidx = lane & 31;    // 8-float column block within the row

  for (int m0 = 0; m0 < n_g; m0 += 64) {
    const int valid = min(64, n_g - m0);

    if (t < 64) ord_s[t] = (m0 + t < n_g) ? order[s0 + m0 + t] : -1;
    __syncthreads();

    // ---- stage A chunk: wave w handles rows [16w,16w+16), 2 rows per iteration ----
#pragma unroll
    for (int it = 0; it < 8; ++it) {
      const int row = (w << 4) + (it << 1) + shalf;
      const int idx = ord_s[row];
      ushort8v hv;
      if (idx >= 0) {
        const float4* src = reinterpret_cast<const float4*>(fnode + (size_t)idx * 256 + cidx * 8);
        const float4 a = src[0];
        const float4 b = src[1];
        hv[0] = f2bf(a.x); hv[1] = f2bf(a.y); hv[2] = f2bf(a.z); hv[3] = f2bf(a.w);
        hv[4] = f2bf(b.x); hv[5] = f2bf(b.y); hv[6] = f2bf(b.z); hv[7] = f2bf(b.w);
      } else {
        hv = (ushort8v)0;
      }
      *reinterpret_cast<ushort8v*>(AsB + (row << 9) + ((cidx << 4) ^ ((row & 7) << 4))) = hv;
    }
    __syncthreads();

    // ---- MFMA: A[64x256] x W2w[128x256]^T -> acc[4 m][8 n] ----
    floatx4 acc[4][8];
#pragma unroll
    for (int mi = 0; mi < 4; ++mi)
#pragma unroll
      for (int nj = 0; nj < 8; ++nj)
        acc[mi][nj] = (floatx4){0.f, 0.f, 0.f, 0.f};

#pragma unroll 1
    for (int kk = 0; kk < 8; ++kk) {
      const int kbyte = kk * 64 + lrow * 16;  // byte offset within a row
      short8 afr[4];
#pragma unroll
      for (int mi = 0; mi < 4; ++mi) {
        const int row = mi * 16 + lcol;
        afr[mi] = *reinterpret_cast<const short8*>(
            AsB + (row << 9) + (kbyte ^ ((row & 7) << 4)));
      }
      const int kof = kk * 32 + lrow * 8;  // element offset in W2 row
#pragma unroll
      for (int nj = 0; nj < 8; ++nj) {
        const short8 bfr = *reinterpret_cast<const short8*>(W2l + (size_t)nj * 4096 + kof);
#pragma unroll
        for (int mi = 0; mi < 4; ++mi)
          acc[mi][nj] = __builtin_amdgcn_mfma_f32_16x16x32_bf16(afr[mi], bfr, acc[mi][nj], 0, 0, 0);
      }
    }

    // ---- epilogue: ex = exp(attn + kb); den += ex; num += (val + vb) * ex ----
#pragma unroll
    for (int mi = 0; mi < 4; ++mi) {
#pragma unroll
      for (int qq = 0; qq < 4; ++qq) {
        const int r = mi * 16 + lrow * 4 + qq;
        const bool mvalid = (r < valid);
#pragma unroll
        for (int nj = 0; nj < 4; ++nj) {
          const float a = acc[mi][nj][qq] + kb[nj];
          const float v = acc[mi][nj + 4][qq] + vb[nj];
          const float e = mvalid ? __expf(a) : 0.f;
          den[nj] += e;
          num[nj] += v * e;
        }
      }
    }
    __syncthreads();  // As/ord_s reads done; safe to restage
  }

  // ---- reduce the 4 row-groups (lanes l, l^16, l^32, l^48 share column d) ----
#pragma unroll
  for (int nj = 0; nj < 4; ++nj) {
    float ds = den[nj], ns = num[nj];
    ds += __shfl_xor(ds, 16, 64);
    ds += __shfl_xor(ds, 32, 64);
    ns += __shfl_xor(ns, 16, 64);
    ns += __shfl_xor(ns, 32, 64);
    if (lrow == 0) fg[(w << 6) + (nj << 4) + lcol] = ns / (ds + 1e-7f);
  }
  __syncthreads();

  // ---- LayerNorm over 256 features, write output row ----
  const float x = fg[t];
  float s = x, s2 = x * x;
#pragma unroll
  for (int o = 32; o > 0; o >>= 1) {
    s += __shfl_xor(s, o, 64);
    s2 += __shfl_xor(s2, o, 64);
  }
  if (lane == 0) { red[w] = s; red[4 + w] = s2; }
  __syncthreads();
  const float ts = red[0] + red[1] + red[2] + red[3];
  const float ts2 = red[4] + red[5] + red[6] + red[7];
  const float mu = ts * (1.f / 256.f);
  const float var = ts2 * (1.f / 256.f) - mu * mu;
  const float inv = rsqrtf(var + 1e-5f);
  out[(size_t)g * 256 + t] = (x - mu) * inv * gamma[t] + beta[t];
}

extern "C" void kernel_launch(void* const* d_in, const int* in_sizes, int n_in,
                              void* d_out, int out_size, void* d_ws, size_t ws_size,
                              hipStream_t stream) {
  const float* f_node   = (const float*)d_in[0];
  const float* key_W    = (const float*)d_in[1];
  const float* key_b    = (const float*)d_in[2];
  const float* value_W  = (const float*)d_in[3];
  const float* value_b  = (const float*)d_in[4];
  const float* gamma    = (const float*)d_in[5];
  const float* beta     = (const float*)d_in[6];
  const int*   graph_id = (const int*)d_in[7];
  const int L = in_sizes[0] / 256;
  const int G = out_size / 256;

  char* ws = (char*)d_ws;
  size_t off = 0;
  int* order = (int*)(ws + off); off += (size_t)L * 4;
  off = (off + 255) & ~(size_t)255;
  int* counts = (int*)(ws + off); off += (size_t)G * 4;
  int* offsets = (int*)(ws + off); off += (size_t)(G + 1) * 4;
  int* cursor = (int*)(ws + off); off += (size_t)G * 4;
  off = (off + 255) & ~(size_t)255;
  unsigned short* W2 = (unsigned short*)(ws + off); off += 512 * 256 * 2;

  k_zero<<<(G + 255) / 256, 256, 0, stream>>>(counts, G);
  k_hist<<<(L + 255) / 256, 256, 0, stream>>>(graph_id, L, counts);
  k_scan<<<1, 1024, 0, stream>>>(counts, offsets, cursor, G);
  k_scatter<<<(L + 255) / 256, 256, 0, stream>>>(graph_id, L, cursor, order);
  k_prepw<<<512, 256, 0, stream>>>(key_W, value_W, W2);
  k_fused<<<G, 256, 0, stream>>>(f_node, W2, key_b, value_b, gamma, beta, order, offsets,
                                 (float*)d_out);
}

// Round 3
// 522.324 us; speedup vs baseline: 1.6372x; 1.2560x over previous
//
#include <hip/hip_runtime.h>

typedef short short8 __attribute__((ext_vector_type(8)));
typedef unsigned short ushort8v __attribute__((ext_vector_type(8)));
typedef float floatx4 __attribute__((ext_vector_type(4)));

__device__ __forceinline__ unsigned short f2bf(float x) {
  union { float f; unsigned int u; } c; c.f = x;
  return (unsigned short)((c.u + 0x7FFFu + ((c.u >> 16) & 1u)) >> 16);
}

__global__ void k_hist(const int* __restrict__ gid, int L, int* __restrict__ counts) {
  int i = blockIdx.x * blockDim.x + threadIdx.x;
  if (i < L) atomicAdd(&counts[gid[i]], 1);
}

// single-block scan of G counts -> exclusive offsets[G+1], cursor = copy of offsets
__global__ void k_scan(const int* __restrict__ counts, int* __restrict__ offsets,
                       int* __restrict__ cursor, int G) {
  __shared__ int sc[1024];
  int t = threadIdx.x;
  int items = (G + 1023) >> 10;
  int base = t * items;
  int s = 0;
  for (int i = 0; i < items; ++i) { int idx = base + i; if (idx < G) s += counts[idx]; }
  sc[t] = s;
  __syncthreads();
  for (int off = 1; off < 1024; off <<= 1) {
    int v = (t >= off) ? sc[t - off] : 0;
    __syncthreads();
    if (t >= off) sc[t] += v;
    __syncthreads();
  }
  int run = (t == 0) ? 0 : sc[t - 1];
  for (int i = 0; i < items; ++i) {
    int idx = base + i;
    if (idx < G) { offsets[idx] = run; cursor[idx] = run; run += counts[idx]; }
  }
  if (t == 1023) offsets[G] = sc[1023];
}

__global__ void k_scatter(const int* __restrict__ gid, int L, int* __restrict__ cursor,
                          int* __restrict__ order) {
  int i = blockIdx.x * blockDim.x + threadIdx.x;
  if (i < L) {
    int g = gid[i];
    int pos = atomicAdd(&cursor[g], 1);
    order[pos] = i;
  }
}

// Combined weight matrix W2 [512][256] bf16, rows interleaved so that
// j2 = 128*w + 64*half + c  maps to  d = 64*w + c   (half 0 = key, 1 = value).
__global__ void k_prepw(const float* __restrict__ keyW, const float* __restrict__ valW,
                        unsigned short* __restrict__ W2) {
  int j2 = blockIdx.x;
  int k = threadIdx.x;
  int wv = j2 >> 7, half = (j2 >> 6) & 1, c = j2 & 63;
  int d = (wv << 6) + c;
  const float* src = half ? valW : keyW;
  W2[j2 * 256 + k] = f2bf(src[d * 256 + k]);
}

__launch_bounds__(256, 2)
__global__ void k_fused(const float* __restrict__ fnode,
                        const unsigned short* __restrict__ W2,
                        const float* __restrict__ key_b, const float* __restrict__ value_b,
                        const float* __restrict__ gamma, const float* __restrict__ beta,
                        const int* __restrict__ order, const int* __restrict__ offsets,
                        float* __restrict__ out) {
  // A tile double buffer: 2 x (64 rows x 256 bf16), linear 512B rows, XOR-swizzled
  __shared__ __align__(16) unsigned short As[2][64 * 256];
  __shared__ float fg[256];
  __shared__ float red[8];

  const int g = blockIdx.x;
  const int t = threadIdx.x;
  const int lane = t & 63;
  const int w = t >> 6;        // wave 0..3 -> d range [64w, 64w+64)
  const int lcol = lane & 15;
  const int lrow = lane >> 4;

  const int s0 = offsets[g];
  const int n_g = offsets[g + 1] - s0;
  const int nchunks = (n_g + 63) >> 6;

  float kb[4], vb[4];
#pragma unroll
  for (int nj = 0; nj < 4; ++nj) {
    int d = (w << 6) + (nj << 4) + lcol;
    kb[nj] = key_b[d];
    vb[nj] = value_b[d];
  }

  float den[4] = {0.f, 0.f, 0.f, 0.f};
  float num[4] = {0.f, 0.f, 0.f, 0.f};

  const unsigned short* W2l = W2 + ((size_t)(w << 7) + lcol) * 256;  // + nj*16*256 + kof

  const int shalf = lane >> 5;   // which of the 2 rows per staging instr
  const int cidx = lane & 31;    // 8-float column block within the row
  const int myrow16 = lane & 15; // ord-prefetch: this lane holds idx for row w*16+myrow16

  float4 ra[8], rb[8];
  int idxp[8];

  for (int c = -1; c < nchunks; ++c) {
    if (c >= 0) __syncthreads();  // As[(c)&1] fully written by previous iteration

    const int nxt = c + 1;

    // ---- issue prefetch of chunk `nxt` into registers (latency hidden by compute) ----
    if (nxt < nchunks) {
      const int gi = (nxt << 6) + (w << 4) + myrow16;
      const int myidx = (gi < n_g) ? order[s0 + gi] : -1;
#pragma unroll
      for (int it = 0; it < 8; ++it) {
        const int ip = __shfl(myidx, (it << 1) + shalf, 64);
        idxp[it] = ip;
        if (ip >= 0) {
          const float4* src =
              reinterpret_cast<const float4*>(fnode + (size_t)ip * 256 + cidx * 8);
          ra[it] = src[0];
          rb[it] = src[1];
        }
      }
    }

    // ---- compute on chunk c from As[c&1] ----
    if (c >= 0) {
      const char* AsB = (const char*)As[c & 1];
      floatx4 acc[4][8];
#pragma unroll
      for (int mi = 0; mi < 4; ++mi)
#pragma unroll
        for (int nj = 0; nj < 8; ++nj)
          acc[mi][nj] = (floatx4){0.f, 0.f, 0.f, 0.f};

#pragma unroll 1
      for (int kk = 0; kk < 8; ++kk) {
        const int kbyte = kk * 64 + lrow * 16;
        short8 afr[4];
#pragma unroll
        for (int mi = 0; mi < 4; ++mi) {
          const int row = mi * 16 + lcol;
          afr[mi] = *reinterpret_cast<const short8*>(
              AsB + (row << 9) + (kbyte ^ ((row & 7) << 4)));
        }
        const int kof = kk * 32 + lrow * 8;
#pragma unroll
        for (int nj = 0; nj < 8; ++nj) {
          const short8 bfr = *reinterpret_cast<const short8*>(W2l + (size_t)nj * 4096 + kof);
#pragma unroll
          for (int mi = 0; mi < 4; ++mi)
            acc[mi][nj] =
                __builtin_amdgcn_mfma_f32_16x16x32_bf16(afr[mi], bfr, acc[mi][nj], 0, 0, 0);
        }
      }

      const int valid = min(64, n_g - (c << 6));
#pragma unroll
      for (int mi = 0; mi < 4; ++mi) {
#pragma unroll
        for (int qq = 0; qq < 4; ++qq) {
          const int r = mi * 16 + lrow * 4 + qq;
          const bool mvalid = (r < valid);
#pragma unroll
          for (int nj = 0; nj < 4; ++nj) {
            const float a = acc[mi][nj][qq] + kb[nj];
            const float v = acc[mi][nj + 4][qq] + vb[nj];
            const float e = mvalid ? __expf(a) : 0.f;
            den[nj] += e;
            num[nj] += v * e;
          }
        }
      }
    }

    // ---- drain prefetch, convert f32->bf16, write As[nxt&1] ----
    if (nxt < nchunks) {
      char* AsB = (char*)As[nxt & 1];
#pragma unroll
      for (int it = 0; it < 8; ++it) {
        const int row = (w << 4) + (it << 1) + shalf;
        ushort8v hv;
        if (idxp[it] >= 0) {
          hv[0] = f2bf(ra[it].x); hv[1] = f2bf(ra[it].y);
          hv[2] = f2bf(ra[it].z); hv[3] = f2bf(ra[it].w);
          hv[4] = f2bf(rb[it].x); hv[5] = f2bf(rb[it].y);
          hv[6] = f2bf(rb[it].z); hv[7] = f2bf(rb[it].w);
        } else {
          hv = (ushort8v)0;
        }
        *reinterpret_cast<ushort8v*>(AsB + (row << 9) + ((cidx << 4) ^ ((row & 7) << 4))) = hv;
      }
    }
  }

  // ---- reduce the 4 row-groups (lanes l, l^16, l^32, l^48 share column d) ----
#pragma unroll
  for (int nj = 0; nj < 4; ++nj) {
    float ds = den[nj], ns = num[nj];
    ds += __shfl_xor(ds, 16, 64);
    ds += __shfl_xor(ds, 32, 64);
    ns += __shfl_xor(ns, 16, 64);
    ns += __shfl_xor(ns, 32, 64);
    if (lrow == 0) fg[(w << 6) + (nj << 4) + lcol] = ns / (ds + 1e-7f);
  }
  __syncthreads();

  // ---- LayerNorm over 256 features, write output row ----
  const float x = fg[t];
  float s = x, s2 = x * x;
#pragma unroll
  for (int o = 32; o > 0; o >>= 1) {
    s += __shfl_xor(s, o, 64);
    s2 += __shfl_xor(s2, o, 64);
  }
  if (lane == 0) { red[w] = s; red[4 + w] = s2; }
  __syncthreads();
  const float ts = red[0] + red[1] + red[2] + red[3];
  const float ts2 = red[4] + red[5] + red[6] + red[7];
  const float mu = ts * (1.f / 256.f);
  const float var = ts2 * (1.f / 256.f) - mu * mu;
  const float inv = rsqrtf(var + 1e-5f);
  out[(size_t)g * 256 + t] = (x - mu) * inv * gamma[t] + beta[t];
}

extern "C" void kernel_launch(void* const* d_in, const int* in_sizes, int n_in,
                              void* d_out, int out_size, void* d_ws, size_t ws_size,
                              hipStream_t stream) {
  const float* f_node   = (const float*)d_in[0];
  const float* key_W    = (const float*)d_in[1];
  const float* key_b    = (const float*)d_in[2];
  const float* value_W  = (const float*)d_in[3];
  const float* value_b  = (const float*)d_in[4];
  const float* gamma    = (const float*)d_in[5];
  const float* beta     = (const float*)d_in[6];
  const int*   graph_id = (const int*)d_in[7];
  const int L = in_sizes[0] / 256;
  const int G = out_size / 256;

  char* ws = (char*)d_ws;
  size_t off = 0;
  int* order = (int*)(ws + off); off += (size_t)L * 4;
  off = (off + 255) & ~(size_t)255;
  int* counts = (int*)(ws + off); off += (size_t)G * 4;
  int* offsets = (int*)(ws + off); off += (size_t)(G + 1) * 4;
  int* cursor = (int*)(ws + off); off += (size_t)G * 4;
  off = (off + 255) & ~(size_t)255;
  unsigned short* W2 = (unsigned short*)(ws + off); off += 512 * 256 * 2;

  hipMemsetAsync(counts, 0, (size_t)G * 4, stream);
  k_hist<<<(L + 255) / 256, 256, 0, stream>>>(graph_id, L, counts);
  k_scan<<<1, 1024, 0, stream>>>(counts, offsets, cursor, G);
  k_scatter<<<(L + 255) / 256, 256, 0, stream>>>(graph_id, L, cursor, order);
  k_prepw<<<512, 256, 0, stream>>>(key_W, value_W, W2);
  k_fused<<<G, 256, 0, stream>>>(f_node, W2, key_b, value_b, gamma, beta, order, offsets,
                                 (float*)d_out);
}

// Round 4
// 450.165 us; speedup vs baseline: 1.8996x; 1.1603x over previous
//
#include <hip/hip_runtime.h>

typedef short short8 __attribute__((ext_vector_type(8)));
typedef float floatx4 __attribute__((ext_vector_type(4)));

#define ORD_CAP 1024

__device__ __forceinline__ unsigned short f2bf(float x) {
  union { float f; unsigned int u; } c; c.f = x;
  return (unsigned short)((c.u + 0x7FFFu + ((c.u >> 16) & 1u)) >> 16);
}

__device__ __forceinline__ unsigned cvtpk(float lo, float hi) {
  unsigned r;
  asm("v_cvt_pk_bf16_f32 %0, %1, %2" : "=v"(r) : "v"(lo), "v"(hi));
  return r;
}

__device__ __forceinline__ void gld16(const void* g, void* l) {
  __builtin_amdgcn_global_load_lds((const __attribute__((address_space(1))) void*)g,
                                   (__attribute__((address_space(3))) void*)l, 16, 0, 0);
}

__global__ void k_hist(const int* __restrict__ gid, int L, int* __restrict__ counts) {
  int i = blockIdx.x * blockDim.x + threadIdx.x;
  if (i < L) atomicAdd(&counts[gid[i]], 1);
}

__global__ void k_scan(const int* __restrict__ counts, int* __restrict__ offsets,
                       int* __restrict__ cursor, int G) {
  __shared__ int sc[1024];
  int t = threadIdx.x;
  int items = (G + 1023) >> 10;
  int base = t * items;
  int s = 0;
  for (int i = 0; i < items; ++i) { int idx = base + i; if (idx < G) s += counts[idx]; }
  sc[t] = s;
  __syncthreads();
  for (int off = 1; off < 1024; off <<= 1) {
    int v = (t >= off) ? sc[t - off] : 0;
    __syncthreads();
    if (t >= off) sc[t] += v;
    __syncthreads();
  }
  int run = (t == 0) ? 0 : sc[t - 1];
  for (int i = 0; i < items; ++i) {
    int idx = base + i;
    if (idx < G) { offsets[idx] = run; cursor[idx] = run; run += counts[idx]; }
  }
  if (t == 1023) offsets[G] = sc[1023];
}

__global__ void k_scatter(const int* __restrict__ gid, int L, int* __restrict__ cursor,
                          int* __restrict__ order) {
  int i = blockIdx.x * blockDim.x + threadIdx.x;
  if (i < L) {
    int g = gid[i];
    int pos = atomicAdd(&cursor[g], 1);
    order[pos] = i;
  }
}

// W2 [512][256] bf16. Row j2: wv = j2>>6 (wave 0..7), half = (j2>>5)&1 (0 key, 1 val),
// c = j2&31, d = 32*wv + c. Wave w's 64 rows cover its d range for both projections.
__global__ void k_prepw(const float* __restrict__ keyW, const float* __restrict__ valW,
                        unsigned short* __restrict__ W2) {
  int j2 = blockIdx.x;
  int k = threadIdx.x;
  int wv = j2 >> 6, half = (j2 >> 5) & 1, c = j2 & 31;
  int d = (wv << 5) + c;
  const float* src = half ? valW : keyW;
  W2[j2 * 256 + k] = f2bf(src[d * 256 + k]);
}

__launch_bounds__(512, 2)
__global__ void k_fused(const float* __restrict__ fnode,
                        const unsigned short* __restrict__ W2,
                        const float* __restrict__ key_b, const float* __restrict__ value_b,
                        const float* __restrict__ gamma, const float* __restrict__ beta,
                        const int* __restrict__ order, const int* __restrict__ offsets,
                        float* __restrict__ out) {
  // A double buffer: 64 rows x 256 f32 (1KB rows), filled by global_load_lds.
  // LDS 16B-slot s of row r holds global slot s ^ (r&7)  (source-side XOR swizzle).
  __shared__ __align__(16) float As[2][64 * 256];
  __shared__ int ord_s[ORD_CAP];
  __shared__ float fg[256];
  __shared__ float red[8];

  const int g = blockIdx.x;
  const int t = threadIdx.x;
  const int lane = t & 63;
  const int w = t >> 6;        // wave 0..7 -> d range [32w, 32w+32)
  const int lcol = lane & 15;
  const int lrow = lane >> 4;

  const int s0 = offsets[g];
  const int n_g = offsets[g + 1] - s0;
  const int nchunks = (n_g + 63) >> 6;

  float kb[2], vb[2];
#pragma unroll
  for (int nj = 0; nj < 2; ++nj) {
    int d = (w << 5) + (nj << 4) + lcol;
    kb[nj] = key_b[d];
    vb[nj] = value_b[d];
  }

  // B fragment bases: nj 0-1 key, 2-3 val (same d as nj-2)
  const unsigned short* Wn[4];
#pragma unroll
  for (int nj = 0; nj < 4; ++nj)
    Wn[nj] = W2 + ((size_t)((w << 6) + ((nj >> 1) << 5) + ((nj & 1) << 4) + lcol)) * 256 +
             lrow * 8;

  // persist B fragments for kk 0..3 in registers (halves per-chunk L2 B-traffic)
  short8 bp[4][4];
#pragma unroll
  for (int nj = 0; nj < 4; ++nj)
#pragma unroll
    for (int kk = 0; kk < 4; ++kk)
      bp[nj][kk] = *reinterpret_cast<const short8*>(Wn[nj] + kk * 32);

  for (int i = t; i < ORD_CAP; i += 512) ord_s[i] = (i < n_g) ? order[s0 + i] : 0;
  __syncthreads();

  float den[2] = {0.f, 0.f};
  float num[2] = {0.f, 0.f};

  // stage: wave w gathers chunk-local rows [8w, 8w+8), one gll (1KB f32 row) each
  auto stage = [&](int c, int bsel) {
    const int m0 = c << 6;
    int idx = 0;
    if (lane < 8) {
      int gi = m0 + (w << 3) + lane;
      idx = ord_s[(gi < n_g) ? gi : 0];
    }
#pragma unroll
    for (int it = 0; it < 8; ++it) {
      const int rid = __shfl(idx, it, 64);
      const int rowl = (w << 3) + it;          // rowl & 7 == it
      const char* gsrc = (const char*)fnode + ((size_t)rid << 10) +
                         ((lane << 4) ^ (it << 4));
      char* ldst = (char*)&As[bsel][0] + (rowl << 10);
      gld16(gsrc, ldst);
    }
  };

  if (nchunks > 0) stage(0, 0);

  for (int c = 0; c < nchunks; ++c) {
    if (c + 1 < nchunks) {
      stage(c + 1, (c + 1) & 1);
      asm volatile("s_waitcnt vmcnt(8)" ::: "memory");  // chunk c's 8 gll retired (FIFO)
    } else {
      asm volatile("s_waitcnt vmcnt(0)" ::: "memory");
    }
    __builtin_amdgcn_s_barrier();  // all waves staged chunk c

    const char* AsB = (const char*)&As[c & 1][0];
    floatx4 acc[4][4];
#pragma unroll
    for (int mi = 0; mi < 4; ++mi)
#pragma unroll
      for (int nj = 0; nj < 4; ++nj)
        acc[mi][nj] = (floatx4){0.f, 0.f, 0.f, 0.f};

#pragma unroll
    for (int kk = 0; kk < 8; ++kk) {
      const int kb2 = kk * 128 + lrow * 32;  // byte offset of this frag's 8 f32
      short8 afr[4];
#pragma unroll
      for (int mi = 0; mi < 4; ++mi) {
        const int row = mi * 16 + lcol;
        const int sw = (row & 7) << 4;
        const floatx4 lo =
            *reinterpret_cast<const floatx4*>(AsB + (row << 10) + (kb2 ^ sw));
        const floatx4 hi =
            *reinterpret_cast<const floatx4*>(AsB + (row << 10) + ((kb2 + 16) ^ sw));
        union { unsigned u[4]; short8 s; } cc;
        cc.u[0] = cvtpk(lo[0], lo[1]);
        cc.u[1] = cvtpk(lo[2], lo[3]);
        cc.u[2] = cvtpk(hi[0], hi[1]);
        cc.u[3] = cvtpk(hi[2], hi[3]);
        afr[mi] = cc.s;
      }
#pragma unroll
      for (int nj = 0; nj < 4; ++nj) {
        short8 bfr;
        if (kk < 4) bfr = bp[nj][kk];
        else bfr = *reinterpret_cast<const short8*>(Wn[nj] + kk * 32);
#pragma unroll
        for (int mi = 0; mi < 4; ++mi)
          acc[mi][nj] =
              __builtin_amdgcn_mfma_f32_16x16x32_bf16(afr[mi], bfr, acc[mi][nj], 0, 0, 0);
      }
    }

    // epilogue: nj 0-1 attn, nj+2 val at same (r,d)
    const int valid = min(64, n_g - (c << 6));
#pragma unroll
    for (int mi = 0; mi < 4; ++mi) {
#pragma unroll
      for (int qq = 0; qq < 4; ++qq) {
        const int r = mi * 16 + lrow * 4 + qq;
        const bool mvalid = (r < valid);
#pragma unroll
        for (int nj = 0; nj < 2; ++nj) {
          const float a = acc[mi][nj][qq] + kb[nj];
          const float v = acc[mi][nj + 2][qq] + vb[nj];
          const float e = mvalid ? __expf(a) : 0.f;
          den[nj] += e;
          num[nj] += v * e;
        }
      }
    }

    asm volatile("" ::: "memory");
    __builtin_amdgcn_s_barrier();  // all waves done reading As[c&1]
  }

  // reduce over the 4 lrow groups (lanes l, l^16, l^32, l^48 share d)
#pragma unroll
  for (int nj = 0; nj < 2; ++nj) {
    float ds = den[nj], ns = num[nj];
    ds += __shfl_xor(ds, 16, 64);
    ds += __shfl_xor(ds, 32, 64);
    ns += __shfl_xor(ns, 16, 64);
    ns += __shfl_xor(ns, 32, 64);
    if (lrow == 0) fg[(w << 5) + (nj << 4) + lcol] = ns / (ds + 1e-7f);
  }
  __syncthreads();

  // LayerNorm over 256 features (first 4 waves carry real data; all run barriers)
  float x = 0.f;
  if (t < 256) x = fg[t];
  float s = x, s2 = x * x;
#pragma unroll
  for (int o = 32; o > 0; o >>= 1) {
    s += __shfl_xor(s, o, 64);
    s2 += __shfl_xor(s2, o, 64);
  }
  if (t < 256 && lane == 0) { red[w] = s; red[4 + w] = s2; }
  __syncthreads();
  if (t < 256) {
    const float ts = red[0] + red[1] + red[2] + red[3];
    const float ts2 = red[4] + red[5] + red[6] + red[7];
    const float mu = ts * (1.f / 256.f);
    const float var = ts2 * (1.f / 256.f) - mu * mu;
    const float inv = rsqrtf(var + 1e-5f);
    out[(size_t)g * 256 + t] = (x - mu) * inv * gamma[t] + beta[t];
  }
}

extern "C" void kernel_launch(void* const* d_in, const int* in_sizes, int n_in,
                              void* d_out, int out_size, void* d_ws, size_t ws_size,
                              hipStream_t stream) {
  const float* f_node   = (const float*)d_in[0];
  const float* key_W    = (const float*)d_in[1];
  const float* key_b    = (const float*)d_in[2];
  const float* value_W  = (const float*)d_in[3];
  const float* value_b  = (const float*)d_in[4];
  const float* gamma    = (const float*)d_in[5];
  const float* beta     = (const float*)d_in[6];
  const int*   graph_id = (const int*)d_in[7];
  const int L = in_sizes[0] / 256;
  const int G = out_size / 256;

  char* ws = (char*)d_ws;
  size_t off = 0;
  int* order = (int*)(ws + off); off += (size_t)L * 4;
  off = (off + 255) & ~(size_t)255;
  int* counts = (int*)(ws + off); off += (size_t)G * 4;
  int* offsets = (int*)(ws + off); off += (size_t)(G + 1) * 4;
  int* cursor = (int*)(ws + off); off += (size_t)G * 4;
  off = (off + 255) & ~(size_t)255;
  unsigned short* W2 = (unsigned short*)(ws + off); off += 512 * 256 * 2;

  hipMemsetAsync(counts, 0, (size_t)G * 4, stream);
  k_hist<<<(L + 255) / 256, 256, 0, stream>>>(graph_id, L, counts);
  k_scan<<<1, 1024, 0, stream>>>(counts, offsets, cursor, G);
  k_scatter<<<(L + 255) / 256, 256, 0, stream>>>(graph_id, L, cursor, order);
  k_prepw<<<512, 256, 0, stream>>>(key_W, value_W, W2);
  k_fused<<<G, 512, 0, stream>>>(f_node, W2, key_b, value_b, gamma, beta, order, offsets,
                                 (float*)d_out);
}

// Round 5
// 376.178 us; speedup vs baseline: 2.2732x; 1.1967x over previous
//
#include <hip/hip_runtime.h>

typedef short short8 __attribute__((ext_vector_type(8)));
typedef float floatx4 __attribute__((ext_vector_type(4)));

#define GPB 8  // graphs per block (consecutive in sorted order)

__device__ __forceinline__ unsigned short f2bf(float x) {
  union { float f; unsigned int u; } c; c.f = x;
  return (unsigned short)((c.u + 0x7FFFu + ((c.u >> 16) & 1u)) >> 16);
}

__device__ __forceinline__ unsigned cvtpk(float lo, float hi) {
  unsigned r;
  asm("v_cvt_pk_bf16_f32 %0, %1, %2" : "=v"(r) : "v"(lo), "v"(hi));
  return r;
}

__device__ __forceinline__ void gld16(const void* g, void* l) {
  __builtin_amdgcn_global_load_lds((const __attribute__((address_space(1))) void*)g,
                                   (__attribute__((address_space(3))) void*)l, 16, 0, 0);
}
__device__ __forceinline__ void gld4(const void* g, void* l) {
  __builtin_amdgcn_global_load_lds((const __attribute__((address_space(1))) void*)g,
                                   (__attribute__((address_space(3))) void*)l, 4, 0, 0);
}

__global__ void k_hist(const int* __restrict__ gid, int L, int* __restrict__ counts) {
  int i = blockIdx.x * blockDim.x + threadIdx.x;
  if (i < L) atomicAdd(&counts[gid[i]], 1);
}

__global__ void k_scan(const int* __restrict__ counts, int* __restrict__ offsets,
                       int* __restrict__ cursor, int G) {
  __shared__ int sc[1024];
  int t = threadIdx.x;
  int items = (G + 1023) >> 10;
  int base = t * items;
  int s = 0;
  for (int i = 0; i < items; ++i) { int idx = base + i; if (idx < G) s += counts[idx]; }
  sc[t] = s;
  __syncthreads();
  for (int off = 1; off < 1024; off <<= 1) {
    int v = (t >= off) ? sc[t - off] : 0;
    __syncthreads();
    if (t >= off) sc[t] += v;
    __syncthreads();
  }
  int run = (t == 0) ? 0 : sc[t - 1];
  for (int i = 0; i < items; ++i) {
    int idx = base + i;
    if (idx < G) { offsets[idx] = run; cursor[idx] = run; run += counts[idx]; }
  }
  if (t == 1023) offsets[G] = sc[1023];
}

__global__ void k_scatter(const int* __restrict__ gid, int L, int* __restrict__ cursor,
                          int* __restrict__ order) {
  int i = blockIdx.x * blockDim.x + threadIdx.x;
  if (i < L) {
    int g = gid[i];
    int pos = atomicAdd(&cursor[g], 1);
    order[pos] = i;
  }
}

// W2 [512][256] bf16. Row j2: wv=j2>>6 (wave), half=(j2>>5)&1 (0 key,1 val), c=j2&31,
// d = 32*wv + c. Wave w's 64 rows cover its 32-col d-range for BOTH projections.
__global__ void k_prepw(const float* __restrict__ keyW, const float* __restrict__ valW,
                        unsigned short* __restrict__ W2) {
  int j2 = blockIdx.x;
  int k = threadIdx.x;
  int wv = j2 >> 6, half = (j2 >> 5) & 1, c = j2 & 31;
  int d = (wv << 5) + c;
  const float* src = half ? valW : keyW;
  W2[j2 * 256 + k] = f2bf(src[d * 256 + k]);
}

__launch_bounds__(512, 2)
__global__ void k_fused(const float* __restrict__ fnode,
                        const unsigned short* __restrict__ W2,
                        const float* __restrict__ key_b, const float* __restrict__ value_b,
                        const float* __restrict__ gamma, const float* __restrict__ beta,
                        const int* __restrict__ order, const int* __restrict__ offsets,
                        float* __restrict__ out, int L, int Gtot) {
  // f32stage: 64 rows x 1KB, gll-filled; 16B-slot s of row r holds global slot s^(r&7).
  // bfA: bf16 dbuf, 64 rows x 512B; 16B-slot j of row r holds logical slot j^(r&7).
  __shared__ __align__(16) float f32stage[64 * 256];
  __shared__ __align__(16) unsigned short bfA[2][64 * 256];
  __shared__ float fg[GPB][256];
  __shared__ int ord_ring[2][64];
  __shared__ int eb[GPB + 1];
  __shared__ float redS[4], redS2[4];

  const int t = threadIdx.x;
  const int lane = t & 63;
  const int w = t >> 6;        // wave 0..7 -> d range [32w, 32w+32)
  const int lcol = lane & 15;
  const int lrow = lane >> 4;
  const int g0 = blockIdx.x * GPB;

  if (t <= GPB) eb[t] = offsets[min(g0 + t, Gtot)];
  __syncthreads();
  const int rbase = eb[0];
  const int nrows = eb[GPB] - rbase;
  const int nc = max(1, (nrows + 63) >> 6);

  float kb[2], vb[2];
#pragma unroll
  for (int nj = 0; nj < 2; ++nj) {
    int d = (w << 5) + (nj << 4) + lcol;
    kb[nj] = key_b[d];
    vb[nj] = value_b[d];
  }

  const unsigned short* Wn[4];
#pragma unroll
  for (int nj = 0; nj < 4; ++nj)
    Wn[nj] = W2 + ((size_t)((w << 6) + ((nj >> 1) << 5) + ((nj & 1) << 4) + lcol)) * 256 +
             lrow * 8;

  short8 bp[4][4];  // kk 0..3 resident in regs; kk 4..7 from L2 per chunk
#pragma unroll
  for (int nj = 0; nj < 4; ++nj)
#pragma unroll
    for (int kk = 0; kk < 4; ++kk)
      bp[nj][kk] = *reinterpret_cast<const short8*>(Wn[nj] + kk * 32);

  float den[2] = {0.f, 0.f};
  float num[2] = {0.f, 0.f};

  // ---- staging helpers ----
  auto stage_ord = [&](int c) {  // order[] values for chunk c -> ord_ring[c&1]; wave 0 only
    if (w == 0) {
      int pos = rbase + (c << 6) + lane;
      if (pos >= L) pos = L - 1;
      gld4(order + pos, &ord_ring[c & 1][0]);
    }
  };
  auto stage_rows = [&](int c) {  // node rows for chunk c -> f32stage (src-XOR swizzled)
#pragma unroll
    for (int it = 0; it < 8; ++it) {
      const int idx = ord_ring[c & 1][(w << 3) + it];
      const char* gsrc =
          (const char*)fnode + ((size_t)idx << 10) + ((lane << 4) ^ (it << 4));
      gld16(gsrc, (char*)f32stage + (((w << 3) + it) << 10));
    }
  };

  int curg = 0;                         // current (unfinalized) graph, block-local
  int ecur = eb[1] - rbase;             // its end row (block-local)
  int flushed = 0;                      // graphs LayerNorm'd so far

  stage_ord(0);
  asm volatile("s_waitcnt vmcnt(0)" ::: "memory");
  __syncthreads();
  stage_rows(0);
  if (nc > 1) stage_ord(1);

  for (int c = 0; c < nc; ++c) {
    const int m0 = c << 6;

    asm volatile("s_waitcnt vmcnt(0)" ::: "memory");
    __syncthreads();  // f32stage(c) + ord_ring ready for all waves

    // ---- cooperative f32 -> bf16 convert into bfA[c&1] ----
    {
      const int r = t >> 3, q = t & 7, x7 = r & 7;
      const char* fsrow = (const char*)f32stage + (r << 10);
      char* bfrow = (char*)&bfA[c & 1][0] + (r << 9);
#pragma unroll
      for (int i = 0; i < 4; ++i) {
        const int S0 = 8 * q + 2 * i;
        const floatx4 a = *(const floatx4*)(fsrow + ((S0 ^ x7) << 4));
        const floatx4 b2 = *(const floatx4*)(fsrow + (((S0 + 1) ^ x7) << 4));
        uint4 o;
        o.x = cvtpk(a[0], a[1]);
        o.y = cvtpk(a[2], a[3]);
        o.z = cvtpk(b2[0], b2[1]);
        o.w = cvtpk(b2[2], b2[3]);
        *(uint4*)(bfrow + (((4 * q + i) ^ x7) << 4)) = o;
      }
    }
    __syncthreads();  // bfA[c&1] ready; f32stage free

    if (c + 1 < nc) {
      stage_rows(c + 1);              // overlaps with compute below
      if (c + 2 < nc) stage_ord(c + 2);
    }

    // ---- MFMA on chunk c ----
    const char* bfb = (const char*)&bfA[c & 1][0];
    floatx4 acc[4][4];
#pragma unroll
    for (int mi = 0; mi < 4; ++mi)
#pragma unroll
      for (int nj = 0; nj < 4; ++nj)
        acc[mi][nj] = (floatx4){0.f, 0.f, 0.f, 0.f};

    __builtin_amdgcn_s_setprio(1);
#pragma unroll
    for (int kk = 0; kk < 8; ++kk) {
      short8 afr[4];
#pragma unroll
      for (int mi = 0; mi < 4; ++mi) {
        const int row = mi * 16 + lcol;
        afr[mi] = *reinterpret_cast<const short8*>(
            bfb + (row << 9) + ((((kk << 2) + lrow) ^ (row & 7)) << 4));
      }
#pragma unroll
      for (int nj = 0; nj < 4; ++nj) {
        const short8 bfr = (kk < 4)
                               ? bp[nj][kk]
                               : *reinterpret_cast<const short8*>(Wn[nj] + (kk << 5));
#pragma unroll
        for (int mi = 0; mi < 4; ++mi)
          acc[mi][nj] =
              __builtin_amdgcn_mfma_f32_16x16x32_bf16(afr[mi], bfr, acc[mi][nj], 0, 0, 0);
      }
    }
    __builtin_amdgcn_s_setprio(0);

    // ---- segmented epilogue: masked accumulate per graph-run (uniform loop) ----
    {
      int lo = 0;
      while (true) {
        const int hi = min(ecur - m0, 64);
#pragma unroll
        for (int mi = 0; mi < 4; ++mi)
#pragma unroll
          for (int qq = 0; qq < 4; ++qq) {
            const int r = mi * 16 + lrow * 4 + qq;
            const bool in = (r >= lo) && (r < hi);
#pragma unroll
            for (int nj = 0; nj < 2; ++nj) {
              const float a = acc[mi][nj][qq] + kb[nj];
              const float v = acc[mi][nj + 2][qq] + vb[nj];
              const float e_ = in ? __expf(a) : 0.f;
              den[nj] += e_;
              num[nj] += v * e_;
            }
          }
        if (ecur <= m0 + 64) {
          // finalize graph curg: reduce over lrow groups, write fg row
#pragma unroll
          for (int nj = 0; nj < 2; ++nj) {
            float ds = den[nj], ns = num[nj];
            ds += __shfl_xor(ds, 16, 64);
            ds += __shfl_xor(ds, 32, 64);
            ns += __shfl_xor(ns, 16, 64);
            ns += __shfl_xor(ns, 32, 64);
            if (lrow == 0)
              fg[curg & (GPB - 1)][(w << 5) + (nj << 4) + lcol] = ns / (ds + 1e-7f);
            den[nj] = 0.f;
            num[nj] = 0.f;
          }
          ++curg;
          lo = hi;
          ecur = (curg < GPB) ? (eb[curg + 1] - rbase) : 0x7fffffff;
        } else
          break;
        if (curg >= GPB) break;
      }
    }

    // ---- LayerNorm + store for graphs completed this chunk (uniform) ----
    if (curg > flushed) {
      __syncthreads();  // fg writes from all waves visible
      for (int j = flushed; j < curg; ++j) {
        float x = 0.f;
        if (t < 256) x = fg[j & (GPB - 1)][t];
        float s = x, s2 = x * x;
#pragma unroll
        for (int o = 32; o > 0; o >>= 1) {
          s += __shfl_xor(s, o, 64);
          s2 += __shfl_xor(s2, o, 64);
        }
        if (t < 256 && lane == 0) { redS[w] = s; redS2[w] = s2; }
        __syncthreads();
        if (t < 256 && (g0 + j) < Gtot) {
          const float ts = redS[0] + redS[1] + redS[2] + redS[3];
          const float ts2 = redS2[0] + redS2[1] + redS2[2] + redS2[3];
          const float mu = ts * (1.f / 256.f);
          const float var = ts2 * (1.f / 256.f) - mu * mu;
          const float inv = rsqrtf(var + 1e-5f);
          out[(size_t)(g0 + j) * 256 + t] = (x - mu) * inv * gamma[t] + beta[t];
        }
        __syncthreads();
      }
      flushed = curg;
    }
  }
}

extern "C" void kernel_launch(void* const* d_in, const int* in_sizes, int n_in,
                              void* d_out, int out_size, void* d_ws, size_t ws_size,
                              hipStream_t stream) {
  const float* f_node   = (const float*)d_in[0];
  const float* key_W    = (const float*)d_in[1];
  const float* key_b    = (const float*)d_in[2];
  const float* value_W  = (const float*)d_in[3];
  const float* value_b  = (const float*)d_in[4];
  const float* gamma    = (const float*)d_in[5];
  const float* beta     = (const float*)d_in[6];
  const int*   graph_id = (const int*)d_in[7];
  const int L = in_sizes[0] / 256;
  const int G = out_size / 256;

  char* ws = (char*)d_ws;
  size_t off = 0;
  int* order = (int*)(ws + off); off += (size_t)L * 4;
  off = (off + 255) & ~(size_t)255;
  int* counts = (int*)(ws + off); off += (size_t)G * 4;
  int* offsets = (int*)(ws + off); off += (size_t)(G + 1) * 4;
  int* cursor = (int*)(ws + off); off += (size_t)G * 4;
  off = (off + 255) & ~(size_t)255;
  unsigned short* W2 = (unsigned short*)(ws + off); off += 512 * 256 * 2;

  hipMemsetAsync(counts, 0, (size_t)G * 4, stream);
  k_hist<<<(L + 255) / 256, 256, 0, stream>>>(graph_id, L, counts);
  k_scan<<<1, 1024, 0, stream>>>(counts, offsets, cursor, G);
  k_scatter<<<(L + 255) / 256, 256, 0, stream>>>(graph_id, L, cursor, order);
  k_prepw<<<512, 256, 0, stream>>>(key_W, value_W, W2);
  const int nblk = (G + GPB - 1) / GPB;
  k_fused<<<nblk, 512, 0, stream>>>(f_node, W2, key_b, value_b, gamma, beta, order,
                                    offsets, (float*)d_out, L, G);
}